// Round 1
// baseline (188.458 us; speedup 1.0000x reference)
//
#include <hip/hip_runtime.h>

#define C_IN 32
#define N_OUT 64
#define H 56
#define W 56
#define TILE 8   // 8x8 output tile per block

typedef _Float16 half4 __attribute__((ext_vector_type(4)));

// Quantize fp32 -> fp16 grid (RNE), return as fp32. Matches float_quantize(EXP=5,MAN=10).
__device__ __forceinline__ float q16(float v) {
    return (float)(_Float16)v;
}

__global__ __launch_bounds__(256, 3) void qconv_kernel(
    const float* __restrict__ x,      // [16,32,56,56]
    const float* __restrict__ weight, // [64,32,3,3]
    const float* __restrict__ bias,   // [64]
    float* __restrict__ out)          // [16,64,56,56]
{
    __shared__ _Float16 sW[C_IN][9][N_OUT];          // 36864 B, [c][i*3+j][n]
    __shared__ float sX[C_IN][TILE + 2][TILE + 2];   // 12800 B

    const int tid = threadIdx.x;
    const int b   = blockIdx.z;
    const int oh0 = blockIdx.y * TILE;
    const int ow0 = blockIdx.x * TILE;

    // ---- stage + quantize weights: weight flat idx = n*288 + c*9 + ij ----
    for (int idx = tid; idx < N_OUT * C_IN * 9; idx += 256) {
        int n   = idx / (C_IN * 9);
        int rem = idx - n * (C_IN * 9);
        int c   = rem / 9;
        int ij  = rem - c * 9;
        sW[c][ij][n] = (_Float16)weight[idx];
    }
    // ---- stage input tile (with zero padding at image borders) ----
    for (int idx = tid; idx < C_IN * (TILE + 2) * (TILE + 2); idx += 256) {
        int c  = idx / 100;
        int r2 = idx - c * 100;
        int rr = r2 / 10;
        int cc = r2 - rr * 10;
        int ih = oh0 + rr - 1;
        int iw = ow0 + cc - 1;
        float v = 0.0f;
        if ((unsigned)ih < (unsigned)H && (unsigned)iw < (unsigned)W)
            v = x[((b * C_IN + c) * H + ih) * W + iw];
        sX[c][rr][cc] = v;
    }
    __syncthreads();

    // thread -> 4 output pixels (one row segment) x 4 output channels
    const int ng   = tid & 15;        // n-group: 16 groups of 4 channels
    const int pg   = tid >> 4;        // pixel-group: 16 groups of 4 pixels
    const int prow = pg >> 1;         // 0..7 (tile row)
    const int pcol = (pg & 1) * 4;    // 0 or 4 (tile col base)
    const int n0   = ng * 4;

    float acc[4][4];                  // [pixel][n], holds fp16-valued fp32
    #pragma unroll
    for (int p = 0; p < 4; ++p)
        #pragma unroll
        for (int n = 0; n < 4; ++n) acc[p][n] = 0.0f;

    for (int c = 0; c < C_IN; ++c) {
        // input window: rows prow..prow+2, cols pcol..pcol+5 of the padded tile
        float xin[3][6];
        #pragma unroll
        for (int i = 0; i < 3; ++i)
            #pragma unroll
            for (int j = 0; j < 6; ++j)
                xin[i][j] = sX[c][prow + i][pcol + j];

        half4 wv[9];
        #pragma unroll
        for (int ij = 0; ij < 9; ++ij)
            wv[ij] = *(const half4*)&sW[c][ij][n0];   // 8B aligned (n0 % 4 == 0)

        // strict k order within this c: ij = 0..8
        #pragma unroll
        for (int ij = 0; ij < 9; ++ij) {
            const int i = ij / 3, j = ij - i * 3;
            #pragma unroll
            for (int p = 0; p < 4; ++p) {
                const float a = xin[i][j + p];
                #pragma unroll
                for (int n = 0; n < 4; ++n) {
                    // prod = f16(a * w) : fp32 multiply then RNE to fp16
                    float prod = q16(a * (float)wv[ij][n]);
                    // acc = f16(acc + prod) : fp32 add then RNE to fp16
                    acc[p][n] = q16(acc[p][n] + prod);
                }
            }
        }
    }

    // epilogue: out = f16(acc + f16(bias)), stored as fp32
    #pragma unroll
    for (int n = 0; n < 4; ++n) {
        const float qb = q16(bias[n0 + n]);
        float4 v;
        v.x = q16(acc[0][n] + qb);
        v.y = q16(acc[1][n] + qb);
        v.z = q16(acc[2][n] + qb);
        v.w = q16(acc[3][n] + qb);
        float* dst = &out[((b * N_OUT + n0 + n) * H + oh0 + prow) * W + ow0 + pcol];
        *(float4*)dst = v;   // ow0+pcol is a multiple of 4 -> 16B aligned
    }
}

extern "C" void kernel_launch(void* const* d_in, const int* in_sizes, int n_in,
                              void* d_out, int out_size, void* d_ws, size_t ws_size,
                              hipStream_t stream) {
    const float* x      = (const float*)d_in[0];
    const float* weight = (const float*)d_in[1];
    const float* bias   = (const float*)d_in[2];
    float* out          = (float*)d_out;

    dim3 grid(W / TILE, H / TILE, 16);  // 7 x 7 x 16
    dim3 block(256);
    qconv_kernel<<<grid, block, 0, stream>>>(x, weight, bias, out);
}

// Round 2
// 180.917 us; speedup vs baseline: 1.0417x; 1.0417x over previous
//
#include <hip/hip_runtime.h>

typedef _Float16 h2 __attribute__((ext_vector_type(2)));
typedef _Float16 h8 __attribute__((ext_vector_type(8)));

#define H 56
#define W 56
#define C_IN 32
#define N_OUT 64
#define K_TOT 288          // 32*9
#define XPITCH 12          // padded sX row pitch (floats): 16B-aligned rows, halo-shifted

// ---- weight transpose + quantize: wq[k][n] fp16, k = c*9+ij < 288, n < 64 ----
__global__ void wtrans_kernel(const float* __restrict__ weight, _Float16* __restrict__ wq) {
    int o = blockIdx.x * 256 + threadIdx.x;   // o = k*64 + n
    int n = o & 63, k = o >> 6;
    wq[o] = (_Float16)weight[n * K_TOT + k];  // weight flat = n*288 + c*9 + ij
}

__global__ __launch_bounds__(128, 2) void qconv_kernel(
    const float* __restrict__ x,        // [16,32,56,56]
    const _Float16* __restrict__ wq,    // [288,64] quantized, transposed
    const float* __restrict__ bias,     // [64]
    float* __restrict__ out)            // [16,64,56,56]
{
    __shared__ __align__(16) _Float16 sW[K_TOT * N_OUT];   // 36864 B, [k][n]
    __shared__ __align__(16) float sX[C_IN * 10 * XPITCH]; // 15360 B -> 52224 B total, 3 blk/CU

    const int tid = threadIdx.x;
    const int b   = blockIdx.z;
    const int oh0 = blockIdx.y * 8;
    const int ow0 = blockIdx.x * 8;

    // ---- stage weights: linear 16B copy, coalesced + conflict-free ----
    {
        const uint4* src = (const uint4*)wq;
        uint4*       dst = (uint4*)sW;
        #pragma unroll
        for (int i = 0; i < 18; ++i)            // 18*128*16B = 36864 B
            dst[i * 128 + tid] = src[i * 128 + tid];
    }
    // ---- stage x tile: 32c x 10r x 10cc (halo-shifted), pitch 12 ----
    for (int idx = tid; idx < C_IN * 100; idx += 128) {
        int c  = idx / 100;
        int r2 = idx - c * 100;
        int rr = r2 / 10;
        int cc = r2 - rr * 10;
        int ih = oh0 + rr - 1;
        int iw = ow0 + cc - 1;
        float v = 0.0f;
        if ((unsigned)ih < (unsigned)H && (unsigned)iw < (unsigned)W)
            v = x[((b * C_IN + c) * H + ih) * W + iw];
        sX[c * (10 * XPITCH) + rr * XPITCH + cc] = v;
    }
    __syncthreads();

    // thread -> 4 pixels (row segment) x 8 output channels
    const int ng   = tid & 7;          // 8 n-groups of 8
    const int seg  = tid >> 3;         // 16 pixel segments
    const int prow = seg >> 1;         // 0..7
    const int pcol = (seg & 1) * 4;    // 0 or 4
    const int n0   = ng * 8;

    h2 acc[4][4];                      // [pixel][n-pair]
    #pragma unroll
    for (int p = 0; p < 4; ++p)
        #pragma unroll
        for (int q = 0; q < 4; ++q) { acc[p][q].x = (_Float16)0.0f; acc[p][q].y = (_Float16)0.0f; }

    for (int c = 0; c < C_IN; ++c) {
        // xin window: 3 rows x 6 floats, vector loads (rows 16B-aligned; pcol in {0,4})
        float xin[3][6];
        const float* base = &sX[c * (10 * XPITCH) + prow * XPITCH + pcol];
        #pragma unroll
        for (int i = 0; i < 3; ++i) {
            float4 v4 = *(const float4*)(base + i * XPITCH);
            float2 v2 = *(const float2*)(base + i * XPITCH + 4);
            xin[i][0] = v4.x; xin[i][1] = v4.y; xin[i][2] = v4.z; xin[i][3] = v4.w;
            xin[i][4] = v2.x; xin[i][5] = v2.y;
        }
        // weights: 9 x b128 (8 fp16 each), broadcast across segments, conflict-free
        const h8* wbase = (const h8*)&sW[(c * 9) * N_OUT + n0];
        h8 wv[9];
        #pragma unroll
        for (int ij = 0; ij < 9; ++ij)
            wv[ij] = wbase[ij * 8];    // stride 64 halves = 8 h8

        // strict k order: ij = 0..8
        #pragma unroll
        for (int ij = 0; ij < 9; ++ij) {
            const int i = ij / 3, j = ij - 3 * i;
            #pragma unroll
            for (int p = 0; p < 4; ++p) {
                const float a = xin[i][j + p];
                #pragma unroll
                for (int q = 0; q < 4; ++q) {
                    h2 pr;
                    // f16(a32*w16): f32 mul, RNE->f16  == v_fma_mixlo/hi_f16
                    pr.x = (_Float16)(a * (float)wv[ij][2 * q]);
                    pr.y = (_Float16)(a * (float)wv[ij][2 * q + 1]);
                    // f16(acc+prod) == v_pk_add_f16 (innocuous double rounding, 24>=2*11+2)
                    acc[p][q] += pr;
                }
            }
        }
    }

    // epilogue: out = f16(acc + f16(bias))
    #pragma unroll
    for (int q = 0; q < 4; ++q) {
        h2 qb;
        qb.x = (_Float16)bias[n0 + 2 * q];
        qb.y = (_Float16)bias[n0 + 2 * q + 1];
        h2 r0 = acc[0][q] + qb;
        h2 r1 = acc[1][q] + qb;
        h2 r2 = acc[2][q] + qb;
        h2 r3 = acc[3][q] + qb;
        float4 vx = { (float)r0.x, (float)r1.x, (float)r2.x, (float)r3.x };
        float4 vy = { (float)r0.y, (float)r1.y, (float)r2.y, (float)r3.y };
        const int n = n0 + 2 * q;
        float* d0 = &out[((b * N_OUT + n) * H + oh0 + prow) * W + ow0 + pcol];
        *(float4*)d0 = vx;
        *(float4*)(d0 + H * W) = vy;
    }
}

extern "C" void kernel_launch(void* const* d_in, const int* in_sizes, int n_in,
                              void* d_out, int out_size, void* d_ws, size_t ws_size,
                              hipStream_t stream) {
    const float* x      = (const float*)d_in[0];
    const float* weight = (const float*)d_in[1];
    const float* bias   = (const float*)d_in[2];
    float* out          = (float*)d_out;
    _Float16* wq        = (_Float16*)d_ws;      // 36864 B scratch

    wtrans_kernel<<<dim3(72), dim3(256), 0, stream>>>(weight, wq);
    qconv_kernel<<<dim3(7, 7, 16), dim3(128), 0, stream>>>(x, wq, bias, out);
}

// Round 3
// 159.000 us; speedup vs baseline: 1.1853x; 1.1378x over previous
//
#include <hip/hip_runtime.h>

typedef _Float16 h2 __attribute__((ext_vector_type(2)));
typedef _Float16 h8 __attribute__((ext_vector_type(8)));

#define H 56
#define W 56
#define C_IN 32
#define N_OUT 64
#define K_TOT 288
#define XPITCH 12    // sX row pitch (floats)
#define XROWS 6      // 4 output rows + 2 halo
#define XCOLS 10     // 8 output cols + 2 halo

// weight transpose + quantize: wq[k][n] fp16, k = c*9+ij, n < 64
__global__ void wtrans_kernel(const float* __restrict__ weight, _Float16* __restrict__ wq) {
    int o = blockIdx.x * 256 + threadIdx.x;   // o = k*64 + n
    int n = o & 63, k = o >> 6;
    wq[o] = (_Float16)weight[n * K_TOT + k];  // weight flat = n*288 + k
}

// f16(a32 * w16): f32 fma (single rounding) + RNE->f16. Pattern-matches
// v_fma_mixlo_f16 / v_fma_mixhi_f16. Innocuous double rounding: 24 >= 2*11+2.
__device__ __forceinline__ h2 qmul2(float a, _Float16 wlo, _Float16 whi) {
    h2 r;
    r.x = (_Float16)__builtin_fmaf(a, (float)wlo, 0.0f);
    r.y = (_Float16)__builtin_fmaf(a, (float)whi, 0.0f);
    return r;
}

__global__ __launch_bounds__(128, 3) void qconv_kernel(
    const float* __restrict__ x,        // [16,32,56,56]
    const _Float16* __restrict__ wq,    // [288,64]
    const float* __restrict__ bias,     // [64]
    float* __restrict__ out)            // [16,64,56,56]
{
    __shared__ __align__(16) float sX[C_IN * XROWS * XPITCH];   // 9216 B

    const int tid = threadIdx.x;
    const int b   = blockIdx.z;
    const int oh0 = blockIdx.y * 4;
    const int ow0 = blockIdx.x * 8;

    // stage x tile: 32c x 6r x 10cc (halo-shifted: col0 = ow0-1, row0 = oh0-1)
    for (int idx = tid; idx < C_IN * XROWS * XCOLS; idx += 128) {
        int c  = idx / (XROWS * XCOLS);
        int r2 = idx - c * (XROWS * XCOLS);
        int rr = r2 / XCOLS;
        int cc = r2 - rr * XCOLS;
        int ih = oh0 + rr - 1;
        int iw = ow0 + cc - 1;
        float v = 0.0f;
        if ((unsigned)ih < (unsigned)H && (unsigned)iw < (unsigned)W)
            v = x[((b * C_IN + c) * H + ih) * W + iw];
        sX[c * (XROWS * XPITCH) + rr * XPITCH + cc] = v;
    }
    __syncthreads();

    // thread -> 2 px (adjacent in w) x 8 output channels
    const int ng   = tid & 7;          // 8 n-groups of 8 channels
    const int seg  = tid >> 3;         // 16 pixel segments (4 rows x 4 col-pairs)
    const int prow = seg >> 2;         // 0..3
    const int pcol = (seg & 3) * 2;    // 0,2,4,6
    const int n0   = ng * 8;

    h2 acc[2][4];
    #pragma unroll
    for (int p = 0; p < 2; ++p)
        #pragma unroll
        for (int q = 0; q < 4; ++q) { acc[p][q].x = (_Float16)0.0f; acc[p][q].y = (_Float16)0.0f; }

    const h8*    wp = (const h8*)wq + ng;               // (c*9+ij)*8 + ng
    const float* xb = &sX[prow * XPITCH + pcol];

    for (int c = 0; c < C_IN; ++c) {
        // x window: 3 rows x 4 cols, two 8B LDS loads per row (8B-aligned)
        float xin[3][4];
        #pragma unroll
        for (int i = 0; i < 3; ++i) {
            float2 lo = *(const float2*)(xb + i * XPITCH);
            float2 hi = *(const float2*)(xb + i * XPITCH + 2);
            xin[i][0] = lo.x; xin[i][1] = lo.y; xin[i][2] = hi.x; xin[i][3] = hi.y;
        }
        // weights: 9 x 16B global loads; wave-unique 128 B, L1-resident
        h8 wv[9];
        #pragma unroll
        for (int ij = 0; ij < 9; ++ij)
            wv[ij] = wp[ij * 8];
        wp += 72;                       // next c: 9*64 halves = 72 h8
        xb += XROWS * XPITCH;

        // strict k order: ij = 0..8 within c, c ascending
        #pragma unroll
        for (int ij = 0; ij < 9; ++ij) {
            const int i = ij / 3, j = ij - 3 * i;
            #pragma unroll
            for (int p = 0; p < 2; ++p) {
                const float a = xin[i][j + p];
                #pragma unroll
                for (int q = 0; q < 4; ++q) {
                    h2 pr = qmul2(a, wv[ij][2 * q], wv[ij][2 * q + 1]);
                    acc[p][q] += pr;    // v_pk_add_f16: RNE16(exact) == ref (24>=2*11+2)
                }
            }
        }
    }

    // epilogue: out = f16(acc + f16(bias))
    const int ohw = (oh0 + prow) * W + ow0 + pcol;
    float* outb = out + (size_t)(b * N_OUT) * (H * W) + ohw;
    #pragma unroll
    for (int q = 0; q < 4; ++q) {
        h2 qb;
        qb.x = (_Float16)bias[n0 + 2 * q];
        qb.y = (_Float16)bias[n0 + 2 * q + 1];
        h2 r0 = acc[0][q] + qb;
        h2 r1 = acc[1][q] + qb;
        float2 v0 = { (float)r0.x, (float)r1.x };
        float2 v1 = { (float)r0.y, (float)r1.y };
        *(float2*)(outb + (n0 + 2 * q)     * (H * W)) = v0;
        *(float2*)(outb + (n0 + 2 * q + 1) * (H * W)) = v1;
    }
}

extern "C" void kernel_launch(void* const* d_in, const int* in_sizes, int n_in,
                              void* d_out, int out_size, void* d_ws, size_t ws_size,
                              hipStream_t stream) {
    const float* x      = (const float*)d_in[0];
    const float* weight = (const float*)d_in[1];
    const float* bias   = (const float*)d_in[2];
    float* out          = (float*)d_out;
    _Float16* wq        = (_Float16*)d_ws;      // 36864 B scratch

    wtrans_kernel<<<dim3(72), dim3(256), 0, stream>>>(weight, wq);
    qconv_kernel<<<dim3(7, 14, 16), dim3(128), 0, stream>>>(x, wq, bias, out);
}

// Round 4
// 149.556 us; speedup vs baseline: 1.2601x; 1.0631x over previous
//
#include <hip/hip_runtime.h>
#include <stdint.h>

typedef _Float16 h2 __attribute__((ext_vector_type(2)));

#define H 56
#define W 56
#define C_IN 32
#define N_OUT 64
#define K_TOT 288
#define XPITCH 12    // sX row pitch (floats), rows 8B-aligned
#define XROWS 6      // 4 output rows + 2 halo
#define XCOLS 10     // 8 output cols + 2 halo

// weight transpose + quantize: wq[k][n] fp16, k = c*9+ij, n < 64
__global__ void wtrans_kernel(const float* __restrict__ weight, _Float16* __restrict__ wq) {
    int o = blockIdx.x * 256 + threadIdx.x;   // o = k*64 + n
    int n = o & 63, k = o >> 6;
    wq[o] = (_Float16)weight[n * K_TOT + k];  // weight flat = n*288 + k
}

// acc2 (packed f16x2) += f16(a_f32 * w_f16) for the two channels in w2.
// v_fma_mixlo/hi: f32 fma, RNE -> f16 half. == ref q16(a*w) (24 >= 2*11+2).
// v_pk_add_f16: RNE16(exact f16+f16 sum) == ref q16(acc+prod).
__device__ __forceinline__ void qmac(float a, uint32_t w2, uint32_t& acc2) {
    uint32_t prod;
    asm("v_fma_mixlo_f16 %1, %2, %3, 0 op_sel_hi:[0,1,0]\n\t"
        "v_fma_mixhi_f16 %1, %2, %3, 0 op_sel:[0,1,0] op_sel_hi:[0,1,0]\n\t"
        "v_pk_add_f16 %0, %0, %1"
        : "+v"(acc2), "=&v"(prod)
        : "v"(a), "v"(w2));
}

__global__ __launch_bounds__(256, 4) void qconv_kernel(
    const float* __restrict__ x,        // [16,32,56,56]
    const _Float16* __restrict__ wq,    // [288,64]
    const float* __restrict__ bias,     // [64]
    float* __restrict__ out)            // [16,64,56,56]
{
    __shared__ __align__(16) float sX[C_IN * XROWS * XPITCH];   // 9216 B

    const int tid = threadIdx.x;
    const int b   = blockIdx.z;
    const int oh0 = blockIdx.y * 4;
    const int ow0 = blockIdx.x * 8;

    // stage x tile: 32c x 6r x 10cc (halo-shifted: cc=0 -> iw=ow0-1, rr=0 -> ih=oh0-1)
    for (int idx = tid; idx < C_IN * XROWS * XCOLS; idx += 256) {
        int c  = idx / (XROWS * XCOLS);
        int r2 = idx - c * (XROWS * XCOLS);
        int rr = r2 / XCOLS;
        int cc = r2 - rr * XCOLS;
        int ih = oh0 + rr - 1;
        int iw = ow0 + cc - 1;
        float v = 0.0f;
        if ((unsigned)ih < (unsigned)H && (unsigned)iw < (unsigned)W)
            v = x[((b * C_IN + c) * H + ih) * W + iw];
        sX[c * (XROWS * XPITCH) + rr * XPITCH + cc] = v;
    }
    __syncthreads();

    // thread -> 2 px (adjacent in w) x 4 output channels
    const int ng   = tid & 15;         // 16 n-groups of 4 channels
    const int seg  = tid >> 4;         // 16 pixel segments (4 rows x 4 col-pairs)
    const int prow = seg >> 2;         // 0..3
    const int pcol = (seg & 3) * 2;    // 0,2,4,6
    const int n0   = ng * 4;

    uint32_t acc[2][2] = {{0u, 0u}, {0u, 0u}};   // [px][ch-pair], packed f16x2

    const uint2* wp = (const uint2*)wq + ng;     // (c*9+ij)*16 + ng
    const float* xb = &sX[prow * XPITCH + pcol];

    for (int c = 0; c < C_IN; ++c) {
        // x window: 3 rows x 4 cols, two 8B LDS loads per row (8B-aligned)
        float xin[3][4];
        #pragma unroll
        for (int i = 0; i < 3; ++i) {
            float2 lo = *(const float2*)(xb + i * XPITCH);
            float2 hi = *(const float2*)(xb + i * XPITCH + 2);
            xin[i][0] = lo.x; xin[i][1] = lo.y; xin[i][2] = hi.x; xin[i][3] = hi.y;
        }
        // weights: 9 x 8B global loads (16 distinct addrs/wave -> 128B, L1-resident)
        uint2 wv[9];
        #pragma unroll
        for (int ij = 0; ij < 9; ++ij)
            wv[ij] = wp[ij * 16];
        wp += 144;                      // next c: 9*64 halves = 144 uint2
        xb += XROWS * XPITCH;

        // strict k order: ij = 0..8 within c, c ascending
        #pragma unroll
        for (int ij = 0; ij < 9; ++ij) {
            const int i = ij / 3, j = ij - 3 * i;
            #pragma unroll
            for (int p = 0; p < 2; ++p) {
                const float a = xin[i][j + p];
                qmac(a, wv[ij].x, acc[p][0]);
                qmac(a, wv[ij].y, acc[p][1]);
            }
        }
    }

    // epilogue: out = f16(acc + f16(bias))
    const int ohw = (oh0 + prow) * W + ow0 + pcol;
    float* outb = out + (size_t)(b * N_OUT + n0) * (H * W) + ohw;
    #pragma unroll
    for (int q = 0; q < 2; ++q) {
        h2 qb;
        qb.x = (_Float16)bias[n0 + 2 * q];
        qb.y = (_Float16)bias[n0 + 2 * q + 1];
        h2 a0 = __builtin_bit_cast(h2, acc[0][q]) + qb;   // v_pk_add_f16
        h2 a1 = __builtin_bit_cast(h2, acc[1][q]) + qb;
        float2 v0 = { (float)a0.x, (float)a1.x };
        float2 v1 = { (float)a0.y, (float)a1.y };
        *(float2*)(outb + (2 * q)     * (H * W)) = v0;
        *(float2*)(outb + (2 * q + 1) * (H * W)) = v1;
    }
}

extern "C" void kernel_launch(void* const* d_in, const int* in_sizes, int n_in,
                              void* d_out, int out_size, void* d_ws, size_t ws_size,
                              hipStream_t stream) {
    const float* x      = (const float*)d_in[0];
    const float* weight = (const float*)d_in[1];
    const float* bias   = (const float*)d_in[2];
    float* out          = (float*)d_out;
    _Float16* wq        = (_Float16*)d_ws;      // 36864 B scratch

    wtrans_kernel<<<dim3(72), dim3(256), 0, stream>>>(weight, wq);
    qconv_kernel<<<dim3(7, 14, 16), dim3(256), 0, stream>>>(x, wq, bias, out);
}

// Round 5
// 145.948 us; speedup vs baseline: 1.2913x; 1.0247x over previous
//
#include <hip/hip_runtime.h>
#include <stdint.h>

typedef _Float16 h2 __attribute__((ext_vector_type(2)));

#define H 56
#define W 56
#define C_IN 32
#define N_OUT 64
#define XPITCH 12    // sX row pitch (floats)
#define XREG 120     // floats per channel region (10 rows * pitch 12)

// weight transpose + quantize into [c][g][ij][m] (g = n>>3, m = n&7), fp16.
// One wave's per-c weight block = 9 uint4 = 144 B, contiguous, uniform.
__global__ void wtrans_kernel(const float* __restrict__ weight, _Float16* __restrict__ wq) {
    int o = blockIdx.x * 256 + threadIdx.x;   // 0 .. 18431
    int m  = o & 7;
    int u  = o >> 3;          // (c*8+g)*9 + ij
    int ij = u % 9;
    int v2 = u / 9;           // c*8 + g
    int g  = v2 & 7;
    int c  = v2 >> 3;
    int n  = g * 8 + m;
    wq[o] = (_Float16)weight[n * 288 + c * 9 + ij];
}

// acc2 (packed f16x2) += f16(a_f32 * w_f16) for 2 channels; w2 lives in an SGPR.
// v_fma_mixlo/hi: f32 fma then RNE->f16  == ref q16(a*w)   (24 >= 2*11+2)
// v_pk_add_f16:   RNE16(exact f16 sum)   == ref q16(acc+p) (24 >= 2*11+2)
__device__ __forceinline__ void qmac_s(float a, uint32_t w2, uint32_t& acc2) {
    uint32_t prod;
    asm("v_fma_mixlo_f16 %1, %2, %3, 0 op_sel_hi:[0,1,0]\n\t"
        "v_fma_mixhi_f16 %1, %2, %3, 0 op_sel:[0,1,0] op_sel_hi:[0,1,0]\n\t"
        "v_pk_add_f16 %0, %0, %1"
        : "+v"(acc2), "=&v"(prod)
        : "v"(a), "s"(w2));
}

__global__ __launch_bounds__(256, 8) void qconv_kernel(
    const float* __restrict__ x,        // [16,32,56,56]
    const uint4* __restrict__ wq,       // [c][g][ij] uint4 (8 fp16 channels)
    const float* __restrict__ bias,     // [64]
    float* __restrict__ out)            // [16,64,56,56]
{
    __shared__ float sX[C_IN * XREG];   // 15360 B: [c][rr][cc], pitch 12, 10x10 window

    const int tid = threadIdx.x;
    const int z   = blockIdx.z;
    const int b   = z >> 1;
    const int oh0 = blockIdx.y * 8;
    const int ow0 = blockIdx.x * 8;

    // ---- stage x tile: 32c x 10r x 10cc, halo-shifted (rr=0 -> ih=oh0-1) ----
    for (int idx = tid; idx < C_IN * 100; idx += 256) {
        int c  = idx / 100;
        int r2 = idx - c * 100;
        int rr = r2 / 10;
        int cc = r2 - rr * 10;
        int ih = oh0 + rr - 1;
        int iw = ow0 + cc - 1;
        float v = 0.0f;
        if ((unsigned)ih < (unsigned)H && (unsigned)iw < (unsigned)W)
            v = x[((b * C_IN + c) * H + ih) * W + iw];
        sX[c * XREG + rr * XPITCH + cc] = v;
    }
    __syncthreads();

    // wave -> 8 output channels, lane -> 1 pixel of the 8x8 tile
    const int wid  = __builtin_amdgcn_readfirstlane(tid >> 6);  // scalar 0..3
    const int g    = (z & 1) * 4 + wid;                         // scalar 0..7
    const int n0   = g * 8;
    const int lane = tid & 63;
    const int r    = lane >> 3;
    const int cl   = lane & 7;

    uint32_t acc[4] = {0u, 0u, 0u, 0u};          // 4 packed f16x2 = 8 channels

    const uint4* wp = wq + g * 9;                // + c*72 per channel step (uniform)
    const float* xb = &sX[r * XPITCH + cl];      // window base (r-1..r+1 rel. output)

    for (int c = 0; c < C_IN; ++c) {
        // own 3x3 window from LDS (2-way banks at pitch 12 -> conflict-free)
        float xw[9];
        #pragma unroll
        for (int dr = 0; dr < 3; ++dr)
            #pragma unroll
            for (int dc = 0; dc < 3; ++dc)
                xw[dr * 3 + dc] = xb[dr * XPITCH + dc];

        // strict k order: ij = 0..8 within c, c ascending
        #pragma unroll
        for (int ij = 0; ij < 9; ++ij) {
            const uint4 w = wp[ij];              // uniform addr -> s_load_dwordx4
            const float a = xw[ij];
            qmac_s(a, w.x, acc[0]);
            qmac_s(a, w.y, acc[1]);
            qmac_s(a, w.z, acc[2]);
            qmac_s(a, w.w, acc[3]);
        }
        wp += 72;                                 // 8 g * 9 ij
        xb += XREG;
    }

    // epilogue: out = f16(acc + f16(bias))
    float* ob = out + (size_t)(b * N_OUT + n0) * (H * W) + (oh0 + r) * W + (ow0 + cl);
    #pragma unroll
    for (int q = 0; q < 4; ++q) {
        h2 qb;
        qb.x = (_Float16)bias[n0 + 2 * q];
        qb.y = (_Float16)bias[n0 + 2 * q + 1];
        h2 s = __builtin_bit_cast(h2, acc[q]) + qb;   // v_pk_add_f16
        ob[(2 * q) * (H * W)]     = (float)s.x;
        ob[(2 * q + 1) * (H * W)] = (float)s.y;
    }
}

extern "C" void kernel_launch(void* const* d_in, const int* in_sizes, int n_in,
                              void* d_out, int out_size, void* d_ws, size_t ws_size,
                              hipStream_t stream) {
    const float* x      = (const float*)d_in[0];
    const float* weight = (const float*)d_in[1];
    const float* bias   = (const float*)d_in[2];
    float* out          = (float*)d_out;
    _Float16* wq        = (_Float16*)d_ws;      // 36864 B scratch

    wtrans_kernel<<<dim3(72), dim3(256), 0, stream>>>(weight, wq);
    qconv_kernel<<<dim3(7, 7, 32), dim3(256), 0, stream>>>(x, (const uint4*)wq, bias, out);
}

// Round 6
// 145.529 us; speedup vs baseline: 1.2950x; 1.0029x over previous
//
#include <hip/hip_runtime.h>
#include <stdint.h>

typedef _Float16 h2 __attribute__((ext_vector_type(2)));

#define H 56
#define W 56
#define C_IN 32
#define N_OUT 64
#define PROW 58            // padded rows
#define PCOL 64            // padded row pitch (floats)
#define NPAD (16 * C_IN * PROW * PCOL)   // 1,900,544 floats
#define NWQ  (C_IN * 5 * 64)             // 10,240 dwords

// ---- prep: zero-padded x restage + weight repack ----
// xpad[b][c][1+ih][1+iw] = x[b][c][ih][iw], zeros elsewhere.
// wq3 dword at ((c*5+t)*64 + n) = packed f16 {w[n][c][2t], w[n][c][2t+1]} (t=4 hi=0).
__global__ void prep_kernel(const float* __restrict__ x, const float* __restrict__ weight,
                            float* __restrict__ xpad, uint32_t* __restrict__ wq3) {
    int idx = blockIdx.x * 256 + threadIdx.x;
    if (idx < NPAD) {
        int col = idx & 63;
        int t   = idx >> 6;
        int row = t % PROW;
        int bc  = t / PROW;          // b*32 + c
        int ih  = row - 1;
        int iw  = col - 1;
        float v = 0.0f;
        if ((unsigned)ih < (unsigned)H && (unsigned)iw < (unsigned)W)
            v = x[(bc * H + ih) * W + iw];
        xpad[idx] = v;
    }
    if (idx < NWQ) {
        int n = idx & 63;
        int u = idx >> 6;            // c*5 + t
        int t = u % 5;
        int c = u / 5;
        int ij0 = 2 * t;
        h2 p;
        p.x = (_Float16)weight[n * 288 + c * 9 + ij0];
        p.y = (t < 4) ? (_Float16)weight[n * 288 + c * 9 + ij0 + 1] : (_Float16)0.0f;
        wq3[idx] = __builtin_bit_cast(uint32_t, p);
    }
}

// acc (f16x2: px0,px1) += f16(a{0,1} * w_half).  a0,a1 wave-uniform (SGPR),
// w per-lane f16 half of a packed VGPR. mixlo/hi: f32 fma then RNE->f16
// == ref q16(a*w); pk_add: RNE16(exact) == ref q16(acc+p). (24 >= 2*11+2)
__device__ __forceinline__ void qmac_lo(float a0, float a1, uint32_t w, uint32_t& acc) {
    uint32_t prod;
    asm("v_fma_mixlo_f16 %1, %2, %4, 0 op_sel_hi:[0,1,0]\n\t"
        "v_fma_mixhi_f16 %1, %3, %4, 0 op_sel_hi:[0,1,0]\n\t"
        "v_pk_add_f16 %0, %0, %1"
        : "+v"(acc), "=&v"(prod)
        : "s"(a0), "s"(a1), "v"(w));
}
__device__ __forceinline__ void qmac_hi(float a0, float a1, uint32_t w, uint32_t& acc) {
    uint32_t prod;
    asm("v_fma_mixlo_f16 %1, %2, %4, 0 op_sel:[0,1,0] op_sel_hi:[0,1,0]\n\t"
        "v_fma_mixhi_f16 %1, %3, %4, 0 op_sel:[0,1,0] op_sel_hi:[0,1,0]\n\t"
        "v_pk_add_f16 %0, %0, %1"
        : "+v"(acc), "=&v"(prod)
        : "s"(a0), "s"(a1), "v"(w));
}

__global__ __launch_bounds__(256, 8) void qconv_kernel(
    const float* __restrict__ xpad,     // [16,32,58,64]
    const uint32_t* __restrict__ wq3,   // [32,5,64]
    const float* __restrict__ bias,     // [64]
    float* __restrict__ out)            // [16,64,56,56]
{
    __shared__ float sOut[4 * 64 * 10];   // 10,240 B: [wid][n][10] (pad 10 vs 8)

    const int tid  = threadIdx.x;
    const int b    = blockIdx.z;
    const int oh0  = blockIdx.y * 4;
    const int ow0  = blockIdx.x * 8;
    const int wid  = __builtin_amdgcn_readfirstlane(tid >> 6);  // 0..3, uniform
    const int lane = tid & 63;                                  // = output channel n
    const int row0 = oh0 + wid;         // output row; padded window rows row0..row0+2

    uint32_t acc[4] = {0u, 0u, 0u, 0u}; // px pairs (0,1)(2,3)(4,5)(6,7), f16x2

    const float*    xbase = xpad + ((size_t)(b * C_IN) * PROW + row0) * PCOL + ow0;
    const uint32_t* wrow  = wq3 + lane;

    for (int c = 0; c < C_IN; ++c) {
        // x window 3x10, wave-uniform addresses -> s_load; one lgkm batch per c
        float a[3][10];
        #pragma unroll
        for (int dr = 0; dr < 3; ++dr)
            #pragma unroll
            for (int dc = 0; dc < 10; ++dc)
                a[dr][dc] = xbase[(c * PROW + dr) * PCOL + dc];

        // per-lane packed weights: 5 coalesced dwords, L1-hot (vmcnt)
        uint32_t w[5];
        #pragma unroll
        for (int t = 0; t < 5; ++t)
            w[t] = wrow[(c * 5 + t) * 64];

        // strict k order: ij = 0..8 within c, c ascending
        #pragma unroll
        for (int ij = 0; ij < 9; ++ij) {
            const int i = ij / 3, j = ij - 3 * i, t = ij >> 1;
            if ((ij & 1) == 0) {
                qmac_lo(a[i][j + 0], a[i][j + 1], w[t], acc[0]);
                qmac_lo(a[i][j + 2], a[i][j + 3], w[t], acc[1]);
                qmac_lo(a[i][j + 4], a[i][j + 5], w[t], acc[2]);
                qmac_lo(a[i][j + 6], a[i][j + 7], w[t], acc[3]);
            } else {
                qmac_hi(a[i][j + 0], a[i][j + 1], w[t], acc[0]);
                qmac_hi(a[i][j + 2], a[i][j + 3], w[t], acc[1]);
                qmac_hi(a[i][j + 4], a[i][j + 5], w[t], acc[2]);
                qmac_hi(a[i][j + 6], a[i][j + 7], w[t], acc[3]);
            }
        }
    }

    // epilogue: add quantized bias, convert to f32, transpose via LDS
    {
        _Float16 qb = (_Float16)bias[lane];
        h2 qb2; qb2.x = qb; qb2.y = qb;
        #pragma unroll
        for (int q = 0; q < 4; ++q) {
            h2 s = __builtin_bit_cast(h2, acc[q]) + qb2;   // v_pk_add_f16
            float2 f; f.x = (float)s.x; f.y = (float)s.y;
            *(float2*)&sOut[(wid * 64 + lane) * 10 + 2 * q] = f;
        }
    }
    __syncthreads();

    // coalesced-ish store: thread t -> (n = t&63, r = t>>6), 8 floats = 2 x dwordx4
    {
        const int n = tid & 63;
        const int r = tid >> 6;
        const float* src = &sOut[(r * 64 + n) * 10];
        float4 v0 = { src[0], src[1], src[2], src[3] };
        float4 v1 = { src[4], src[5], src[6], src[7] };
        float* dst = out + ((size_t)(b * N_OUT + n) * H + oh0 + r) * W + ow0;
        *(float4*)dst = v0;
        *(float4*)(dst + 4) = v1;
    }
}

extern "C" void kernel_launch(void* const* d_in, const int* in_sizes, int n_in,
                              void* d_out, int out_size, void* d_ws, size_t ws_size,
                              hipStream_t stream) {
    const float* x      = (const float*)d_in[0];
    const float* weight = (const float*)d_in[1];
    const float* bias   = (const float*)d_in[2];
    float* out          = (float*)d_out;

    float*    xpad = (float*)d_ws;                       // 7,602,176 B
    uint32_t* wq3  = (uint32_t*)((char*)d_ws + (size_t)NPAD * 4);  // 40,960 B

    prep_kernel<<<dim3(NPAD / 256), dim3(256), 0, stream>>>(x, weight, xpad, wq3);
    qconv_kernel<<<dim3(7, 14, 16), dim3(256), 0, stream>>>(xpad, wq3, bias, out);
}

// Round 7
// 85.712 us; speedup vs baseline: 2.1987x; 1.6979x over previous
//
#include <hip/hip_runtime.h>
#include <stdint.h>

typedef _Float16 f16x8 __attribute__((ext_vector_type(8)));
typedef float    f32x4 __attribute__((ext_vector_type(4)));

#define H 56
#define W 56
#define C_IN 32
#define N_OUT 64
#define PR 58                       // padded rows (1+56+1)
#define PC 68                       // padded f16 cols (2 left, 56, 10 right) = 34 dwords
#define NPD (16 * C_IN * PR * 34)   // xpad16 dwords = 1,011,712
#define LCS 124                     // LDS f16 per channel region (6 rows * 20 + 4 pad)
#define NWF 9216                    // wq_frag dwords = 9 ij * 4 nt * 64 lane * 4 dw

__device__ __forceinline__ float q16f(float v) { return (float)(_Float16)v; }

// zero-padded f16 x: xp dword at ((b*32+c)*58+row)*34+d holds cols {2d,2d+1},
// where col = iw+2 (2-col left pad keeps dword loads aligned at ow0-2).
__global__ void prep_x(const float* __restrict__ x, uint32_t* __restrict__ xp) {
    int idx = blockIdx.x * 256 + threadIdx.x;
    if (idx >= NPD) return;
    int d   = idx % 34;
    int t   = idx / 34;
    int row = t % PR;
    int bc  = t / PR;               // b*32 + c
    int ih  = row - 1;
    int iw0 = 2 * d - 2, iw1 = 2 * d - 1;
    _Float16 lo = (_Float16)0.f, hi = (_Float16)0.f;
    if ((unsigned)ih < (unsigned)H) {
        const float* src = x + (size_t)(bc * H + ih) * W;
        if ((unsigned)iw0 < (unsigned)W) lo = (_Float16)src[iw0];
        if ((unsigned)iw1 < (unsigned)W) hi = (_Float16)src[iw1];
    }
    xp[idx] = (uint32_t)__builtin_bit_cast(uint16_t, lo) |
              ((uint32_t)__builtin_bit_cast(uint16_t, hi) << 16);
}

// weights pre-swizzled into MFMA B-fragment order:
// dword o = ((ij*4+nt)*64 + lane)*4 + j2 -> {w[n][c0][ij], w[n][c0+1][ij]},
// n = nt*16 + (lane&15), c0 = (lane>>4)*8 + 2*j2.   B[k=c][n], k = quad*8+j.
__global__ void prep_w(const float* __restrict__ weight, uint32_t* __restrict__ wf) {
    int o = blockIdx.x * 256 + threadIdx.x;
    if (o >= NWF) return;
    int j2   = o & 3;
    int lane = (o >> 2) & 63;
    int u    = o >> 8;              // ij*4 + nt
    int nt   = u & 3;
    int ij   = u >> 2;
    int n    = nt * 16 + (lane & 15);
    int c0   = (lane >> 4) * 8 + 2 * j2;
    _Float16 lo = (_Float16)weight[n * 288 + c0 * 9 + ij];
    _Float16 hi = (_Float16)weight[n * 288 + (c0 + 1) * 9 + ij];
    wf[o] = (uint32_t)__builtin_bit_cast(uint16_t, lo) |
            ((uint32_t)__builtin_bit_cast(uint16_t, hi) << 16);
}

// block = 4 waves; wave = one oh row x 16 ow x all 64 n.
// conv as 9 shifted K=32 GEMMs: acc[nt] += A_shift(16px x 32c) * B_shift(32c x 16n).
__global__ __launch_bounds__(256, 4) void conv_mfma(
    const uint32_t* __restrict__ xp,    // [b][c][58][34] dwords
    const f16x8*    __restrict__ wf,    // B-fragment layout
    const float*    __restrict__ bias,  // [64]
    float* __restrict__ out)            // [16,64,56,56]
{
    __shared__ uint32_t sX[C_IN * (LCS / 2)];   // 32 * 62 dwords = 7936 B

    const int tid = threadIdx.x;
    const int b   = blockIdx.z;
    const int oh0 = blockIdx.y * 4;
    const int ow0 = blockIdx.x * 16;

    // stage 32c x 6 rows x 20 cols (f16), dword-granular, coalesced
    {
        const int base_src = ((b * C_IN) * PR + oh0) * 34 + (ow0 >> 1);
        for (int i = tid; i < C_IN * 60; i += 256) {
            int c = i / 60, rem = i - c * 60;
            int r = rem / 10, d = rem - r * 10;
            sX[c * 62 + r * 10 + d] = xp[base_src + (c * PR + r) * 34 + d];
        }
    }
    __syncthreads();

    const int wid  = tid >> 6;          // 0..3 -> oh row
    const int lane = tid & 63;
    const int quad = lane >> 4;
    const int m    = lane & 15;         // A row = px (ow offset)
    const int oh   = oh0 + wid;

    const _Float16* sxh = (const _Float16*)sX;
    // A element (c, shift i,jj): sxh[c*124 + (wid+i)*20 + (m+jj+1)]
    // frag k = quad*8 + t  ->  base covers quad; t,i,jj are immediate offsets.
    const int abase = quad * (8 * LCS) + wid * 20 + m + 1;

    f32x4 acc[4] = {{0,0,0,0},{0,0,0,0},{0,0,0,0},{0,0,0,0}};

    #pragma unroll
    for (int ij = 0; ij < 9; ++ij) {
        const int i  = ij / 3, jj = ij - 3 * i;
        const int sh = i * 20 + jj;

        f16x8 bfr[4];
        #pragma unroll
        for (int nt = 0; nt < 4; ++nt)
            bfr[nt] = wf[(ij * 4 + nt) * 64 + lane];   // global_load_dwordx4, L2-hot

        f16x8 af;
        #pragma unroll
        for (int t = 0; t < 8; ++t)
            af[t] = sxh[abase + sh + t * LCS];         // ds_read_u16, imm offsets

        #pragma unroll
        for (int nt = 0; nt < 4; ++nt)
            acc[nt] = __builtin_amdgcn_mfma_f32_16x16x32_f16(af, bfr[nt], acc[nt], 0, 0, 0);
    }

    // epilogue: out = q16(acc + q16(bias)); C/D: col(lane&15)=n, row(quad*4+reg)=px
    const int ncol = lane & 15;
    #pragma unroll
    for (int nt = 0; nt < 4; ++nt) {
        const int n  = nt * 16 + ncol;
        const float qb = q16f(bias[n]);
        float* ob = out + ((size_t)(b * N_OUT + n) * H + oh) * W;
        #pragma unroll
        for (int reg = 0; reg < 4; ++reg) {
            const int ow = ow0 + quad * 4 + reg;
            if (ow < W) ob[ow] = q16f(acc[nt][reg] + qb);
        }
    }
}

extern "C" void kernel_launch(void* const* d_in, const int* in_sizes, int n_in,
                              void* d_out, int out_size, void* d_ws, size_t ws_size,
                              hipStream_t stream) {
    const float* x      = (const float*)d_in[0];
    const float* weight = (const float*)d_in[1];
    const float* bias   = (const float*)d_in[2];
    float* out          = (float*)d_out;

    uint32_t* xp = (uint32_t*)d_ws;                          // 4,046,848 B
    uint32_t* wfp = (uint32_t*)((char*)d_ws + (size_t)NPD * 4);  // 36,864 B

    prep_x<<<dim3((NPD + 255) / 256), dim3(256), 0, stream>>>(x, xp);
    prep_w<<<dim3((NWF + 255) / 256), dim3(256), 0, stream>>>(weight, wfp);
    conv_mfma<<<dim3(4, 14, 16), dim3(256), 0, stream>>>(xp, (const f16x8*)wfp, bias, out);
}

// Round 8
// 73.621 us; speedup vs baseline: 2.5598x; 1.1642x over previous
//
#include <hip/hip_runtime.h>
#include <stdint.h>

typedef _Float16 f16x8 __attribute__((ext_vector_type(8)));
typedef float    f32x4 __attribute__((ext_vector_type(4)));

#define H 56
#define W 56
#define C_IN 32
#define N_OUT 64
#define PR 58                 // padded rows, row = ih+1
#define PCOLS 66              // padded cols, col = iw+1; cols 57..65 stay zero
#define XB_BLOCKS (16 * PR)   // 928 transpose blocks
#define NWF 9216              // wf dwords: 9 ij * 4 nt * 64 lane * 4 dw
#define XPAD_BYTES ((size_t)16 * PR * PCOLS * C_IN * 2)   // 3,919,872 (256-aligned)

__device__ __forceinline__ float q16f(float v) { return (float)(_Float16)v; }

// merged prep: blocks [0,928) transpose x to channel-innermost f16 with zero
// padding; blocks [928, 964) pack weights into MFMA A-fragment order.
__global__ __launch_bounds__(256) void prep_kernel(
    const float* __restrict__ x, const float* __restrict__ weight,
    _Float16* __restrict__ xpad, uint32_t* __restrict__ wf)
{
    const int nb  = blockIdx.x;
    const int tid = threadIdx.x;
    if (nb < XB_BLOCKS) {
        // one block = one (b,row): x[b][c][ih][iw] -> xpad[b][row][col][c]
        __shared__ _Float16 sT[PCOLS * 34];   // col stride 34 f16 (17 dw) kills conflicts
        for (int i = tid; i < PCOLS * 17; i += 256) ((uint32_t*)sT)[i] = 0u;
        __syncthreads();
        const int b = nb / PR, row = nb % PR, ih = row - 1;
        if ((unsigned)ih < (unsigned)H) {
            #pragma unroll
            for (int k = 0; k < 7; ++k) {       // 7*256 = 1792 = 32c * 56iw
                int idx = k * 256 + tid;
                int c = idx / W, iw = idx - c * W;
                sT[(iw + 1) * 34 + c] = (_Float16)x[((b * C_IN + c) * H + ih) * W + iw];
            }
        }
        __syncthreads();
        uint32_t* dst = (uint32_t*)(xpad + ((size_t)b * PR + row) * PCOLS * C_IN);
        for (int i = tid; i < PCOLS * 16; i += 256) {   // 1056 dwords, coalesced
            int col = i >> 4, cd = i & 15;
            dst[i] = ((const uint32_t*)sT)[col * 17 + cd];
        }
    } else {
        // A-frag pack: dword o = ((ij*4+nt)*64 + lane)*4 + t2
        // A[m=lane&15 -> n = nt*16+m][k=(lane>>4)*8 + 2*t2 + {0,1} -> c]
        int o = (nb - XB_BLOCKS) * 256 + tid;           // < 9216
        int t2   = o & 3;
        int lane = (o >> 2) & 63;
        int u    = o >> 8;
        int nt   = u & 3, ij = u >> 2;
        int n    = nt * 16 + (lane & 15);
        int c0   = (lane >> 4) * 8 + 2 * t2;
        _Float16 lo = (_Float16)weight[n * 288 + c0 * 9 + ij];
        _Float16 hi = (_Float16)weight[n * 288 + (c0 + 1) * 9 + ij];
        wf[o] = (uint32_t)__builtin_bit_cast(uint16_t, lo) |
                ((uint32_t)__builtin_bit_cast(uint16_t, hi) << 16);
    }
}

// conv as 9 shifted K=32 GEMMs, no LDS, no barrier.
// wave = 1 oh row x 16 ow x 64 n; D[m=n(16/tile)][col=px].
__global__ __launch_bounds__(256, 4) void conv_mfma(
    const _Float16* __restrict__ xpad,   // [16][58][66][32] f16
    const f16x8*    __restrict__ wf,     // A-fragment layout
    const float*    __restrict__ bias,   // [64]
    float* __restrict__ out)             // [16,64,56,56]
{
    const int tid  = threadIdx.x;
    const int b    = blockIdx.z;
    const int oh   = blockIdx.y * 4 + (tid >> 6);
    const int ow0  = blockIdx.x * 16;
    const int lane = tid & 63;
    const int quad = lane >> 4;
    const int px   = lane & 15;

    // B-frag base: B[k=c][n=px], k = quad*8+t -> 16 contiguous bytes per load
    const _Float16* xb = xpad + (((size_t)b * PR + oh) * PCOLS + ow0 + px) * C_IN + quad * 8;

    f32x4 acc[4] = {{0,0,0,0},{0,0,0,0},{0,0,0,0},{0,0,0,0}};

    #pragma unroll
    for (int ij = 0; ij < 9; ++ij) {
        const int i = ij / 3, jj = ij - 3 * i;
        f16x8 xf = *(const f16x8*)(xb + (i * PCOLS + jj) * C_IN);   // global_load_dwordx4, L1-hot
        #pragma unroll
        for (int nt = 0; nt < 4; ++nt) {
            f16x8 wv = wf[(ij * 4 + nt) * 64 + lane];               // dwordx4, L1/L2-hot
            acc[nt] = __builtin_amdgcn_mfma_f32_16x16x32_f16(wv, xf, acc[nt], 0, 0, 0);
        }
    }

    // epilogue: out = q16(acc + q16(bias)); quarter-wave = one full 64B line
    const int ow = ow0 + px;
    if (ow < W) {
        #pragma unroll
        for (int nt = 0; nt < 4; ++nt) {
            #pragma unroll
            for (int reg = 0; reg < 4; ++reg) {
                const int n = nt * 16 + quad * 4 + reg;
                out[((size_t)(b * N_OUT + n) * H + oh) * W + ow] =
                    q16f(acc[nt][reg] + q16f(bias[n]));
            }
        }
    }
}

extern "C" void kernel_launch(void* const* d_in, const int* in_sizes, int n_in,
                              void* d_out, int out_size, void* d_ws, size_t ws_size,
                              hipStream_t stream) {
    const float* x      = (const float*)d_in[0];
    const float* weight = (const float*)d_in[1];
    const float* bias   = (const float*)d_in[2];
    float* out          = (float*)d_out;

    _Float16* xpad = (_Float16*)d_ws;
    uint32_t* wfp  = (uint32_t*)((char*)d_ws + XPAD_BYTES);   // 36,864 B

    prep_kernel<<<dim3(XB_BLOCKS + NWF / 256), dim3(256), 0, stream>>>(x, weight, xpad, wfp);
    conv_mfma<<<dim3(4, 14, 16), dim3(256), 0, stream>>>(xpad, (const f16x8*)wfp, bias, out);
}

// Round 9
// 71.827 us; speedup vs baseline: 2.6238x; 1.0250x over previous
//
#include <hip/hip_runtime.h>
#include <stdint.h>

typedef _Float16 f16x8 __attribute__((ext_vector_type(8)));
typedef float    f32x4 __attribute__((ext_vector_type(4)));

#define H 56
#define W 56
#define C_IN 32
#define N_OUT 64
#define PR 58                 // padded rows, row = ih+1
#define PCOLS 66              // padded cols, col = iw+1; cols 57..65 stay zero
#define XB_BLOCKS (16 * PR)   // 928 transpose blocks
#define NWF 9216              // wf dwords: 9 ij * 4 nt * 64 lane * 4 dw
#define XPAD_BYTES ((size_t)16 * PR * PCOLS * C_IN * 2)   // 3,919,872 (256-aligned)

__device__ __forceinline__ float q16f(float v) { return (float)(_Float16)v; }

// merged prep: blocks [0,928) transpose x to channel-innermost f16 with zero
// padding; blocks [928, 964) pack weights into MFMA A-fragment order.
__global__ __launch_bounds__(256) void prep_kernel(
    const float* __restrict__ x, const float* __restrict__ weight,
    _Float16* __restrict__ xpad, uint32_t* __restrict__ wf)
{
    const int nb  = blockIdx.x;
    const int tid = threadIdx.x;
    if (nb < XB_BLOCKS) {
        // one block = one (b,row): x[b][c][ih][iw] -> xpad[b][row][col][c]
        __shared__ _Float16 sT[PCOLS * 34];   // col stride 34 f16 (17 dw) kills conflicts
        for (int i = tid; i < PCOLS * 17; i += 256) ((uint32_t*)sT)[i] = 0u;
        __syncthreads();
        const int b = nb / PR, row = nb % PR, ih = row - 1;
        if ((unsigned)ih < (unsigned)H) {
            #pragma unroll
            for (int k = 0; k < 7; ++k) {       // 7*256 = 1792 = 32c * 56iw
                int idx = k * 256 + tid;
                int c = idx / W, iw = idx - c * W;
                sT[(iw + 1) * 34 + c] = (_Float16)x[((b * C_IN + c) * H + ih) * W + iw];
            }
        }
        __syncthreads();
        uint32_t* dst = (uint32_t*)(xpad + ((size_t)b * PR + row) * PCOLS * C_IN);
        for (int i = tid; i < PCOLS * 16; i += 256) {   // 1056 dwords, coalesced
            int col = i >> 4, cd = i & 15;
            dst[i] = ((const uint32_t*)sT)[col * 17 + cd];
        }
    } else {
        // A-frag pack: dword o = ((ij*4+nt)*64 + lane)*4 + t2
        // A[m=lane&15 -> n = nt*16+m][k=(lane>>4)*8 + 2*t2 + {0,1} -> c]
        int o = (nb - XB_BLOCKS) * 256 + tid;           // < 9216
        int t2   = o & 3;
        int lane = (o >> 2) & 63;
        int u    = o >> 8;
        int nt   = u & 3, ij = u >> 2;
        int n    = nt * 16 + (lane & 15);
        int c0   = (lane >> 4) * 8 + 2 * t2;
        _Float16 lo = (_Float16)weight[n * 288 + c0 * 9 + ij];
        _Float16 hi = (_Float16)weight[n * 288 + (c0 + 1) * 9 + ij];
        wf[o] = (uint32_t)__builtin_bit_cast(uint16_t, lo) |
                ((uint32_t)__builtin_bit_cast(uint16_t, hi) << 16);
    }
}

// conv as 9 shifted K=32 GEMMs, no LDS, no barrier.
// wave = 1 oh row x 32 ow (two 16-px B-frag groups sharing A) x 64 n.
__global__ __launch_bounds__(256, 2) void conv_mfma(
    const _Float16* __restrict__ xpad,   // [16][58][66][32] f16
    const f16x8*    __restrict__ wf,     // A-fragment layout
    const float*    __restrict__ bias,   // [64]
    float* __restrict__ out)             // [16,64,56,56]
{
    const int tid  = threadIdx.x;
    const int b    = blockIdx.z;
    const int oh   = blockIdx.y * 4 + (tid >> 6);
    const int bx   = blockIdx.x;
    const int ow0  = bx * 24;            // tiles cover ow 0-31 and 24-55
    const int lane = tid & 63;
    const int quad = lane >> 4;
    const int px   = lane & 15;

    // B-frag bases: B[k=c][n=px], k = quad*8+t -> 16 contiguous bytes per load
    const _Float16* xb0 = xpad + (((size_t)b * PR + oh) * PCOLS + ow0 + px) * C_IN + quad * 8;
    const _Float16* xb1 = xb0 + 16 * C_IN;

    f32x4 acc[2][4] = {{{0,0,0,0},{0,0,0,0},{0,0,0,0},{0,0,0,0}},
                       {{0,0,0,0},{0,0,0,0},{0,0,0,0},{0,0,0,0}}};

    #pragma unroll
    for (int ij = 0; ij < 9; ++ij) {
        const int i = ij / 3, jj = ij - 3 * i;
        const int sh = (i * PCOLS + jj) * C_IN;
        f16x8 xf0 = *(const f16x8*)(xb0 + sh);              // dwordx4, L1-hot
        f16x8 xf1 = *(const f16x8*)(xb1 + sh);
        #pragma unroll
        for (int nt = 0; nt < 4; ++nt) {
            f16x8 wv = wf[(ij * 4 + nt) * 64 + lane];       // dwordx4, L1/L2-hot
            acc[0][nt] = __builtin_amdgcn_mfma_f32_16x16x32_f16(wv, xf0, acc[0][nt], 0, 0, 0);
            acc[1][nt] = __builtin_amdgcn_mfma_f32_16x16x32_f16(wv, xf1, acc[1][nt], 0, 0, 0);
        }
    }

    // epilogue: out = q16(acc + q16(bias)); quarter-wave = one full 64B line.
    // overlap columns 24..31 are owned by tile bx==0.
    #pragma unroll
    for (int xg = 0; xg < 2; ++xg) {
        const int ow = ow0 + 16 * xg + px;
        if (bx == 0 || ow >= 32) {
            #pragma unroll
            for (int nt = 0; nt < 4; ++nt) {
                #pragma unroll
                for (int reg = 0; reg < 4; ++reg) {
                    const int n = nt * 16 + quad * 4 + reg;
                    out[((size_t)(b * N_OUT + n) * H + oh) * W + ow] =
                        q16f(acc[xg][nt][reg] + q16f(bias[n]));
                }
            }
        }
    }
}

extern "C" void kernel_launch(void* const* d_in, const int* in_sizes, int n_in,
                              void* d_out, int out_size, void* d_ws, size_t ws_size,
                              hipStream_t stream) {
    const float* x      = (const float*)d_in[0];
    const float* weight = (const float*)d_in[1];
    const float* bias   = (const float*)d_in[2];
    float* out          = (float*)d_out;

    _Float16* xpad = (_Float16*)d_ws;
    uint32_t* wfp  = (uint32_t*)((char*)d_ws + XPAD_BYTES);   // 36,864 B

    prep_kernel<<<dim3(XB_BLOCKS + NWF / 256), dim3(256), 0, stream>>>(x, weight, xpad, wfp);
    conv_mfma<<<dim3(2, 14, 16), dim3(256), 0, stream>>>(xpad, (const f16x8*)wfp, bias, out);
}